// Round 1
// baseline (289.189 us; speedup 1.0000x reference)
//
#include <hip/hip_runtime.h>
#include <hip/hip_bf16.h>
#include <math.h>
#include <float.h>

#define N_PTS 16384
#define NVERT 6890
#define RESO 256
#define C_LAT 192
#define VIEW_DIM 27

#define NCHUNK 16
#define CHUNK 431   // 16*431 = 6896 >= 6890

// ---------------- latent transpose: [C][H][W] -> [H][W][C] ----------------
__global__ __launch_bounds__(256) void transpose_latent(const float* __restrict__ lat,
                                                        float* __restrict__ latT) {
    __shared__ float tile[C_LAT][65];
    int b = blockIdx.x;            // 1024 blocks
    int y = b >> 2;
    int x0 = (b & 3) << 6;
    int t = threadIdx.x;
    #pragma unroll
    for (int i = 0; i < (C_LAT * 64) / 256; ++i) {   // 48 iters
        int e = i * 256 + t;
        int c = e >> 6, xi = e & 63;
        tile[c][xi] = lat[c * (RESO * RESO) + y * RESO + x0 + xi];
    }
    __syncthreads();
    #pragma unroll
    for (int i = 0; i < (C_LAT * 64) / 256; ++i) {
        int e = i * 256 + t;
        int xi = e / C_LAT, c = e % C_LAT;
        latT[(size_t)(y * RESO + x0 + xi) * C_LAT + c] = tile[c][xi];
    }
}

// ---------------- nearest-neighbor partial argmin ----------------
__global__ __launch_bounds__(256) void nn_partial(const float* __restrict__ P,
                                                  const float* __restrict__ V,
                                                  float* __restrict__ pd2,
                                                  int* __restrict__ pidx) {
    __shared__ float4 vs[CHUNK];
    int t = threadIdx.x;
    int pc = blockIdx.x;   // 0..63
    int vc = blockIdx.y;   // 0..15
    int vstart = vc * CHUNK;
    int count = min(CHUNK, NVERT - vstart);
    for (int i = t; i < count; i += 256) {
        int g = vstart + i;
        float x = V[g * 3 + 0], y = V[g * 3 + 1], z = V[g * 3 + 2];
        float v2 = __fadd_rn(__fadd_rn(__fmul_rn(x, x), __fmul_rn(y, y)), __fmul_rn(z, z));
        vs[i] = make_float4(x, y, z, v2);
    }
    __syncthreads();
    int n = pc * 256 + t;
    float px = P[n * 3 + 0], py = P[n * 3 + 1], pz = P[n * 3 + 2];
    float p2 = __fadd_rn(__fadd_rn(__fmul_rn(px, px), __fmul_rn(py, py)), __fmul_rn(pz, pz));
    float best = FLT_MAX;
    int bi = 0;
    for (int v = 0; v < count; ++v) {
        float4 q = vs[v];
        // match XLA: dot = fma(z,vz, fma(y,vy, x*vx)); d2 = (p2+v2) - 2*dot
        float dot = fmaf(pz, q.z, fmaf(py, q.y, __fmul_rn(px, q.x)));
        float d2 = __fsub_rn(__fadd_rn(p2, q.w), __fmul_rn(2.0f, dot));
        if (d2 < best) { best = d2; bi = vstart + v; }
    }
    pd2[n * NCHUNK + vc] = best;
    pidx[n * NCHUNK + vc] = bi;
}

// ---------------- weight padding ----------------
__global__ __launch_bounds__(256) void prep_weights(const float* __restrict__ w0,
                                                    const float* __restrict__ w2,
                                                    float* __restrict__ Wp0,
                                                    float* __restrict__ Wp2) {
    int i = blockIdx.x * 256 + threadIdx.x;
    if (i < 256 * 128) {
        int nn = i >> 7, k = i & 127;
        Wp0[i] = (k < 127) ? w0[nn * 127 + k] : 0.0f;
    }
    if (i < 256 * 352) {
        int nn = i / 352, k = i % 352;
        Wp2[i] = (k < 347) ? w2[nn * 347 + k] : 0.0f;
    }
}

// ---------------- reduce partials + bilinear + embed ----------------
__global__ __launch_bounds__(256) void sample_embed(const float* __restrict__ pd2,
                                                    const int* __restrict__ pidx,
                                                    const float* __restrict__ vts_uv,
                                                    const float* __restrict__ latT,
                                                    const float* __restrict__ view_dir,
                                                    float* __restrict__ X1,
                                                    float* __restrict__ X2) {
    int t = threadIdx.x;
    int lane = t & 63, w = t >> 6;
    int n = blockIdx.x * 4 + w;
    float best = FLT_MAX;
    int bi = 0;
    #pragma unroll
    for (int c = 0; c < NCHUNK; ++c) {
        float d = pd2[n * NCHUNK + c];
        int ix = pidx[n * NCHUNK + c];
        if (d < best) { best = d; bi = ix; }
    }
    float u = vts_uv[bi * 2 + 0], vv = vts_uv[bi * 2 + 1];
    float h = __fsqrt_rn(fmaxf(best, 1e-12f));
    float hn = __fmul_rn(__fadd_rn(__fdiv_rn(h, 0.1f), 1.0f), 0.5f);

    float fsum = 0.0f;
    #pragma unroll
    for (int p = 0; p < 3; ++p) {
        float xc = (p == 2) ? hn : u;
        float yc = (p == 1) ? hn : vv;
        float x = fminf(fmaxf(xc, 0.0f), 1.0f) * 255.0f;
        float y = fminf(fmaxf(yc, 0.0f), 1.0f) * 255.0f;
        float x0 = floorf(x), y0 = floorf(y);
        float wx = x - x0, wy = y - y0;
        int x0i = min(max((int)x0, 0), 255), y0i = min(max((int)y0, 0), 255);
        int x1i = min(x0i + 1, 255), y1i = min(y0i + 1, 255);
        int co = p * 64 + lane;
        float f00 = latT[(size_t)(y0i * 256 + x0i) * C_LAT + co];
        float f01 = latT[(size_t)(y0i * 256 + x1i) * C_LAT + co];
        float f10 = latT[(size_t)(y1i * 256 + x0i) * C_LAT + co];
        float f11 = latT[(size_t)(y1i * 256 + x1i) * C_LAT + co];
        fsum += f00 * (1 - wx) * (1 - wy) + f01 * wx * (1 - wy) + f10 * (1 - wx) * wy + f11 * wx * wy;
    }
    float fused = fsum / 3.0f;
    X1[(size_t)n * 128 + lane] = fused;
    X2[(size_t)n * 352 + 283 + lane] = fused;

    if (lane < 63) {
        float val;
        if (lane < 3) {
            val = (lane == 0) ? h : ((lane == 1) ? u : vv);
        } else {
            int e = lane - 3;
            if (e < 30) {
                int d = e / 10, k = e % 10;
                float pv = (d == 0) ? h : ((d == 1) ? u : vv);
                val = sinf(pv * (float)(1 << k));
            } else {
                e -= 30;
                int d = e / 10, k = e % 10;
                float pv = (d == 0) ? h : ((d == 1) ? u : vv);
                val = cosf(pv * (float)(1 << k));
            }
        }
        X1[(size_t)n * 128 + 64 + lane] = val;
    } else {
        X1[(size_t)n * 128 + 127] = 0.0f;
    }
    if (lane < 27) {
        X2[(size_t)n * 352 + 256 + lane] = view_dir[n * VIEW_DIM + lane];
    } else if (lane < 32) {
        X2[(size_t)n * 352 + 347 + (lane - 27)] = 0.0f;
    }
}

// ---------------- fp32 tiled GEMM: Y = relu(X * W^T + b) ----------------
// X: [M][ldx] (K used), W: [N][ldw] (row n = output n), Y: [M][ldy]
__global__ __launch_bounds__(256) void gemm_relu(const float* __restrict__ X,
                                                 const float* __restrict__ W,
                                                 const float* __restrict__ bias,
                                                 float* __restrict__ Y,
                                                 int K, int ldx, int ldw, int ldy) {
    __shared__ __align__(16) float Xs[32][68];
    __shared__ __align__(16) float Ws[32][68];
    int t = threadIdx.x;
    int bm = blockIdx.x, bn = blockIdx.y;
    int tx = t & 15, ty = t >> 4;
    float acc[4][4];
    #pragma unroll
    for (int i = 0; i < 4; ++i)
        #pragma unroll
        for (int j = 0; j < 4; ++j) acc[i][j] = 0.0f;

    for (int kt = 0; kt < K; kt += 32) {
        #pragma unroll
        for (int i = 0; i < 8; ++i) {
            int e = i * 256 + t;
            int ml = e >> 5, kl = e & 31;
            Xs[kl][ml] = X[(size_t)(bm * 64 + ml) * ldx + kt + kl];
            Ws[kl][ml] = W[(size_t)(bn * 64 + ml) * ldw + kt + kl];
        }
        __syncthreads();
        #pragma unroll
        for (int kk = 0; kk < 32; ++kk) {
            float4 a = *(const float4*)&Xs[kk][ty * 4];
            float4 b = *(const float4*)&Ws[kk][tx * 4];
            acc[0][0] = fmaf(a.x, b.x, acc[0][0]); acc[0][1] = fmaf(a.x, b.y, acc[0][1]);
            acc[0][2] = fmaf(a.x, b.z, acc[0][2]); acc[0][3] = fmaf(a.x, b.w, acc[0][3]);
            acc[1][0] = fmaf(a.y, b.x, acc[1][0]); acc[1][1] = fmaf(a.y, b.y, acc[1][1]);
            acc[1][2] = fmaf(a.y, b.z, acc[1][2]); acc[1][3] = fmaf(a.y, b.w, acc[1][3]);
            acc[2][0] = fmaf(a.z, b.x, acc[2][0]); acc[2][1] = fmaf(a.z, b.y, acc[2][1]);
            acc[2][2] = fmaf(a.z, b.z, acc[2][2]); acc[2][3] = fmaf(a.z, b.w, acc[2][3]);
            acc[3][0] = fmaf(a.w, b.x, acc[3][0]); acc[3][1] = fmaf(a.w, b.y, acc[3][1]);
            acc[3][2] = fmaf(a.w, b.z, acc[3][2]); acc[3][3] = fmaf(a.w, b.w, acc[3][3]);
        }
        __syncthreads();
    }
    #pragma unroll
    for (int i = 0; i < 4; ++i) {
        int row = bm * 64 + ty * 4 + i;
        int col = bn * 64 + tx * 4;
        float4 v;
        v.x = acc[i][0] + bias[col + 0];
        v.y = acc[i][1] + bias[col + 1];
        v.z = acc[i][2] + bias[col + 2];
        v.w = acc[i][3] + bias[col + 3];
        v.x = fmaxf(v.x, 0.0f); v.y = fmaxf(v.y, 0.0f);
        v.z = fmaxf(v.z, 0.0f); v.w = fmaxf(v.w, 0.0f);
        *(float4*)&Y[(size_t)row * ldy + col] = v;
    }
}

// ---------------- alpha + rgb heads ----------------
__global__ __launch_bounds__(256) void finalize(const float* __restrict__ X2,
                                                const float* __restrict__ A4,
                                                const float* __restrict__ w_alpha,
                                                const float* __restrict__ b_alpha,
                                                const float* __restrict__ w_rgb,
                                                const float* __restrict__ b_rgb,
                                                float* __restrict__ out) {
    int t = threadIdx.x;
    int lane = t & 63, w = t >> 6;
    int n = blockIdx.x * 4 + w;
    float sa = 0.0f;
    #pragma unroll
    for (int i = 0; i < 4; ++i) sa = fmaf(X2[(size_t)n * 352 + lane + 64 * i], w_alpha[lane + 64 * i], sa);
    float sr = 0.0f, sg = 0.0f, sb = 0.0f;
    #pragma unroll
    for (int i = 0; i < 2; ++i) {
        float a4 = A4[(size_t)n * 128 + lane + 64 * i];
        sr = fmaf(a4, w_rgb[0 * 128 + lane + 64 * i], sr);
        sg = fmaf(a4, w_rgb[1 * 128 + lane + 64 * i], sg);
        sb = fmaf(a4, w_rgb[2 * 128 + lane + 64 * i], sb);
    }
    #pragma unroll
    for (int off = 32; off; off >>= 1) {
        sa += __shfl_xor(sa, off, 64);
        sr += __shfl_xor(sr, off, 64);
        sg += __shfl_xor(sg, off, 64);
        sb += __shfl_xor(sb, off, 64);
    }
    if (lane == 0) {
        out[(size_t)n * 4 + 0] = sa + b_alpha[0];
        out[(size_t)n * 4 + 1] = sr + b_rgb[0];
        out[(size_t)n * 4 + 2] = sg + b_rgb[1];
        out[(size_t)n * 4 + 3] = sb + b_rgb[2];
    }
}

extern "C" void kernel_launch(void* const* d_in, const int* in_sizes, int n_in,
                              void* d_out, int out_size, void* d_ws, size_t ws_size,
                              hipStream_t stream) {
    (void)in_sizes; (void)n_in; (void)out_size; (void)ws_size;
    const float* sampled_pts  = (const float*)d_in[0];
    const float* smpl_verts   = (const float*)d_in[1];
    const float* view_dir     = (const float*)d_in[2];
    const float* input_latent = (const float*)d_in[3];
    const float* vts_uv       = (const float*)d_in[4];
    const float* w_geo0 = (const float*)d_in[5];
    const float* b_geo0 = (const float*)d_in[6];
    const float* w_geo1 = (const float*)d_in[7];
    const float* b_geo1 = (const float*)d_in[8];
    const float* w_alpha = (const float*)d_in[9];
    const float* b_alpha = (const float*)d_in[10];
    const float* w_view0 = (const float*)d_in[11];
    const float* b_view0 = (const float*)d_in[12];
    const float* w_view1 = (const float*)d_in[13];
    const float* b_view1 = (const float*)d_in[14];
    const float* w_rgb = (const float*)d_in[15];
    const float* b_rgb = (const float*)d_in[16];

    char* ws = (char*)d_ws;
    size_t off = 0;
    float* latT = (float*)(ws + off); off += (size_t)C_LAT * RESO * RESO * 4;        // 50.33 MB
    float* pd2  = (float*)(ws + off); off += (size_t)N_PTS * NCHUNK * 4;             // 1 MB
    int*   pidx = (int*)  (ws + off); off += (size_t)N_PTS * NCHUNK * 4;             // 1 MB
    float* X1   = (float*)(ws + off); size_t offX1 = off; off += (size_t)N_PTS * 128 * 4;  // 8.4 MB
    float* A1   = (float*)(ws + off); size_t offA1 = off; off += (size_t)N_PTS * 256 * 4;  // 16.8 MB
    float* X2   = (float*)(ws + off); off += (size_t)N_PTS * 352 * 4;                // 23 MB
    float* Wp0  = (float*)(ws + off); off += (size_t)256 * 128 * 4;
    float* Wp2  = (float*)(ws + off); off += (size_t)256 * 352 * 4;
    float* A3   = (float*)((char*)d_ws + offA1);   // overlay A1 (dead after K2)
    float* A4   = (float*)((char*)d_ws + offX1);   // overlay X1 (dead after K1)

    float* out = (float*)d_out;

    hipLaunchKernelGGL(transpose_latent, dim3(1024), dim3(256), 0, stream, input_latent, latT);
    hipLaunchKernelGGL(nn_partial, dim3(64, 16), dim3(256), 0, stream,
                       sampled_pts, smpl_verts, pd2, pidx);
    hipLaunchKernelGGL(prep_weights, dim3(352), dim3(256), 0, stream, w_geo0, w_view0, Wp0, Wp2);
    hipLaunchKernelGGL(sample_embed, dim3(4096), dim3(256), 0, stream,
                       pd2, pidx, vts_uv, latT, view_dir, X1, X2);
    // L0: X1[16384,128] * Wp0[256,128]^T -> A1 [16384,256]
    hipLaunchKernelGGL(gemm_relu, dim3(N_PTS / 64, 4), dim3(256), 0, stream,
                       X1, Wp0, b_geo0, A1, 128, 128, 128, 256);
    // L1: A1 * w_geo1[256,256]^T -> X2 cols 0..255
    hipLaunchKernelGGL(gemm_relu, dim3(N_PTS / 64, 4), dim3(256), 0, stream,
                       A1, w_geo1, b_geo1, X2, 256, 256, 256, 352);
    // L2: X2[16384,352] * Wp2[256,352]^T -> A3 [16384,256]
    hipLaunchKernelGGL(gemm_relu, dim3(N_PTS / 64, 4), dim3(256), 0, stream,
                       X2, Wp2, b_view0, A3, 352, 352, 352, 256);
    // L3: A3 * w_view1[128,256]^T -> A4 [16384,128]
    hipLaunchKernelGGL(gemm_relu, dim3(N_PTS / 64, 2), dim3(256), 0, stream,
                       A3, w_view1, b_view1, A4, 256, 256, 256, 128);
    hipLaunchKernelGGL(finalize, dim3(4096), dim3(256), 0, stream,
                       X2, A4, w_alpha, b_alpha, w_rgb, b_rgb, out);
}

// Round 3
// 200.497 us; speedup vs baseline: 1.4424x; 1.4424x over previous
//
#include <hip/hip_runtime.h>
#include <hip/hip_bf16.h>
#include <math.h>
#include <float.h>

#define N_PTS 16384
#define NVERT 6890
#define RESO 256
#define C_LAT 192
#define VIEW_DIM 27

#define NCHUNK 16
#define CHUNK 431   // 16*431 = 6896 >= 6890

typedef __hip_bfloat16 bf16;
typedef __bf16 bf16x8 __attribute__((ext_vector_type(8)));
typedef float f32x4 __attribute__((ext_vector_type(4)));

__device__ __forceinline__ void gload_lds16(const void* g, void* l) {
    __builtin_amdgcn_global_load_lds(
        (const __attribute__((address_space(1))) unsigned int*)g,
        (__attribute__((address_space(3))) unsigned int*)l, 16, 0, 0);
}

// ---------------- latent transpose: [C][H][W] fp32 -> [H][W][C] bf16 ----------------
__global__ __launch_bounds__(256) void transpose_latent(const float* __restrict__ lat,
                                                        bf16* __restrict__ latT) {
    __shared__ float tile[C_LAT][65];
    int b = blockIdx.x;            // 1024 blocks
    int y = b >> 2;
    int x0 = (b & 3) << 6;
    int t = threadIdx.x;
    #pragma unroll
    for (int i = 0; i < (C_LAT * 64) / 256; ++i) {   // 48 iters
        int e = i * 256 + t;
        int c = e >> 6, xi = e & 63;
        tile[c][xi] = lat[c * (RESO * RESO) + y * RESO + x0 + xi];
    }
    __syncthreads();
    #pragma unroll
    for (int i = 0; i < (C_LAT * 64) / 256; ++i) {
        int e = i * 256 + t;
        int xi = e / C_LAT, c = e % C_LAT;
        latT[(size_t)(y * RESO + x0 + xi) * C_LAT + c] = __float2bfloat16(tile[c][xi]);
    }
}

// ---------------- nearest-neighbor partial argmin (exact ref arithmetic) ----------------
__global__ __launch_bounds__(256) void nn_partial(const float* __restrict__ P,
                                                  const float* __restrict__ V,
                                                  float* __restrict__ pd2,
                                                  int* __restrict__ pidx) {
    __shared__ float4 vs[CHUNK];
    int t = threadIdx.x;
    int pc = blockIdx.x;   // 0..63
    int vc = blockIdx.y;   // 0..15
    int vstart = vc * CHUNK;
    int count = min(CHUNK, NVERT - vstart);
    for (int i = t; i < count; i += 256) {
        int g = vstart + i;
        float x = V[g * 3 + 0], y = V[g * 3 + 1], z = V[g * 3 + 2];
        float v2 = __fadd_rn(__fadd_rn(__fmul_rn(x, x), __fmul_rn(y, y)), __fmul_rn(z, z));
        vs[i] = make_float4(x, y, z, v2);
    }
    __syncthreads();
    int n = pc * 256 + t;
    float px = P[n * 3 + 0], py = P[n * 3 + 1], pz = P[n * 3 + 2];
    float p2 = __fadd_rn(__fadd_rn(__fmul_rn(px, px), __fmul_rn(py, py)), __fmul_rn(pz, pz));
    float best = FLT_MAX;
    int bi = 0;
    for (int v = 0; v < count; ++v) {
        float4 q = vs[v];
        float dot = fmaf(pz, q.z, fmaf(py, q.y, __fmul_rn(px, q.x)));
        float d2 = __fsub_rn(__fadd_rn(p2, q.w), __fmul_rn(2.0f, dot));
        if (d2 < best) { best = d2; bi = vstart + v; }
    }
    pd2[n * NCHUNK + vc] = best;
    pidx[n * NCHUNK + vc] = bi;
}

// ---------------- weight conversion/padding to bf16 ----------------
__global__ __launch_bounds__(256) void prep_weights(const float* __restrict__ w0,
                                                    const float* __restrict__ w1,
                                                    const float* __restrict__ w2,
                                                    const float* __restrict__ w3,
                                                    bf16* __restrict__ Wp0,
                                                    bf16* __restrict__ W1b,
                                                    bf16* __restrict__ Wp2,
                                                    bf16* __restrict__ W3b) {
    int i = blockIdx.x * 256 + threadIdx.x;
    if (i < 256 * 128) {
        int nn = i >> 7, k = i & 127;
        Wp0[i] = __float2bfloat16((k < 127) ? w0[nn * 127 + k] : 0.0f);
    }
    if (i < 256 * 256) {
        W1b[i] = __float2bfloat16(w1[i]);
    }
    if (i < 256 * 352) {
        int nn = i / 352, k = i % 352;
        Wp2[i] = __float2bfloat16((k < 347) ? w2[nn * 347 + k] : 0.0f);
    }
    if (i < 128 * 256) {
        W3b[i] = __float2bfloat16(w3[i]);
    }
}

// ---------------- reduce partials + bilinear + embed (bf16 outputs) ----------------
__global__ __launch_bounds__(256) void sample_embed(const float* __restrict__ pd2,
                                                    const int* __restrict__ pidx,
                                                    const float* __restrict__ vts_uv,
                                                    const bf16* __restrict__ latT,
                                                    const float* __restrict__ view_dir,
                                                    bf16* __restrict__ X1,
                                                    bf16* __restrict__ X2) {
    int t = threadIdx.x;
    int lane = t & 63, w = t >> 6;
    int n = blockIdx.x * 4 + w;
    float best = FLT_MAX;
    int bi = 0;
    #pragma unroll
    for (int c = 0; c < NCHUNK; ++c) {
        float d = pd2[n * NCHUNK + c];
        int ix = pidx[n * NCHUNK + c];
        if (d < best) { best = d; bi = ix; }
    }
    float u = vts_uv[bi * 2 + 0], vv = vts_uv[bi * 2 + 1];
    float h = __fsqrt_rn(fmaxf(best, 1e-12f));
    float hn = __fmul_rn(__fadd_rn(__fdiv_rn(h, 0.1f), 1.0f), 0.5f);

    float fsum = 0.0f;
    #pragma unroll
    for (int p = 0; p < 3; ++p) {
        float xc = (p == 2) ? hn : u;
        float yc = (p == 1) ? hn : vv;
        float x = fminf(fmaxf(xc, 0.0f), 1.0f) * 255.0f;
        float y = fminf(fmaxf(yc, 0.0f), 1.0f) * 255.0f;
        float x0 = floorf(x), y0 = floorf(y);
        float wx = x - x0, wy = y - y0;
        int x0i = min(max((int)x0, 0), 255), y0i = min(max((int)y0, 0), 255);
        int x1i = min(x0i + 1, 255), y1i = min(y0i + 1, 255);
        int co = p * 64 + lane;
        float f00 = __bfloat162float(latT[(size_t)(y0i * 256 + x0i) * C_LAT + co]);
        float f01 = __bfloat162float(latT[(size_t)(y0i * 256 + x1i) * C_LAT + co]);
        float f10 = __bfloat162float(latT[(size_t)(y1i * 256 + x0i) * C_LAT + co]);
        float f11 = __bfloat162float(latT[(size_t)(y1i * 256 + x1i) * C_LAT + co]);
        fsum += f00 * (1 - wx) * (1 - wy) + f01 * wx * (1 - wy) + f10 * (1 - wx) * wy + f11 * wx * wy;
    }
    float fused = fsum / 3.0f;
    X1[(size_t)n * 128 + lane] = __float2bfloat16(fused);
    X2[(size_t)n * 352 + 283 + lane] = __float2bfloat16(fused);

    if (lane < 63) {
        float val;
        if (lane < 3) {
            val = (lane == 0) ? h : ((lane == 1) ? u : vv);
        } else {
            int e = lane - 3;
            if (e < 30) {
                int d = e / 10, k = e % 10;
                float pv = (d == 0) ? h : ((d == 1) ? u : vv);
                val = sinf(pv * (float)(1 << k));
            } else {
                e -= 30;
                int d = e / 10, k = e % 10;
                float pv = (d == 0) ? h : ((d == 1) ? u : vv);
                val = cosf(pv * (float)(1 << k));
            }
        }
        X1[(size_t)n * 128 + 64 + lane] = __float2bfloat16(val);
    } else {
        X1[(size_t)n * 128 + 127] = __float2bfloat16(0.0f);
    }
    if (lane < 27) {
        X2[(size_t)n * 352 + 256 + lane] = __float2bfloat16(view_dir[n * VIEW_DIM + lane]);
    } else if (lane < 32) {
        X2[(size_t)n * 352 + 347 + (lane - 27)] = __float2bfloat16(0.0f);
    }
}

// ---------------- bf16 MFMA GEMM: Y = relu(X * W^T + b), BM=BN=128, BK=32 ----------------
// X: [M][LDX] bf16, W: [N][LDW] bf16 (row n = output n), Y: [M][LDY] bf16
// 4 waves in 2x2; per wave 64x64 via 4x4 frags of 16x16x32 MFMA.
// LDS swizzle: 16B slot s at row r holds k-group g = s ^ ((r>>1)&3)  (involution),
// pre-applied on the global source so global_load_lds stays linear-dest.
template<int K, int LDX, int LDW, int LDY>
__global__ __launch_bounds__(256) void gemm_mfma(const bf16* __restrict__ X,
                                                 const bf16* __restrict__ W,
                                                 const float* __restrict__ bias,
                                                 bf16* __restrict__ Y) {
    __shared__ char smem[16384];
    const int t = threadIdx.x;
    const int bm = blockIdx.x, bn = blockIdx.y;
    const int l = t & 63, w = t >> 6;
    const int wr = w >> 1, wc = w & 1;
    const int lr = l & 15, lg = l >> 4;

    f32x4 acc[4][4];
    #pragma unroll
    for (int m = 0; m < 4; ++m)
        #pragma unroll
        for (int n = 0; n < 4; ++n) acc[m][n] = f32x4{0.f, 0.f, 0.f, 0.f};

    #pragma unroll
    for (int kt = 0; kt < K; kt += 32) {
        __syncthreads();
        #pragma unroll
        for (int i = 0; i < 2; ++i) {
            int p = i * 256 + t;           // 16B unit
            int r = p >> 2, s = p & 3;
            int g = s ^ ((r >> 1) & 3);
            gload_lds16(X + (size_t)(bm * 128 + r) * LDX + kt + g * 8, smem + p * 16);
        }
        #pragma unroll
        for (int i = 0; i < 2; ++i) {
            int p = i * 256 + t;
            int r = p >> 2, s = p & 3;
            int g = s ^ ((r >> 1) & 3);
            gload_lds16(W + (size_t)(bn * 128 + r) * LDW + kt + g * 8, smem + 8192 + p * 16);
        }
        __syncthreads();
        bf16x8 af[4], bw[4];
        #pragma unroll
        for (int m = 0; m < 4; ++m) {
            int rr = wr * 64 + m * 16 + lr;
            int slot = lg ^ ((rr >> 1) & 3);
            af[m] = *(const bf16x8*)(smem + rr * 64 + slot * 16);
        }
        #pragma unroll
        for (int n = 0; n < 4; ++n) {
            int rr = wc * 64 + n * 16 + lr;
            int slot = lg ^ ((rr >> 1) & 3);
            bw[n] = *(const bf16x8*)(smem + 8192 + rr * 64 + slot * 16);
        }
        #pragma unroll
        for (int m = 0; m < 4; ++m)
            #pragma unroll
            for (int n = 0; n < 4; ++n)
                acc[m][n] = __builtin_amdgcn_mfma_f32_16x16x32_bf16(af[m], bw[n], acc[m][n], 0, 0, 0);
    }

    #pragma unroll
    for (int n = 0; n < 4; ++n) {
        int col = bn * 128 + wc * 64 + n * 16 + lr;
        float bv = bias[col];
        #pragma unroll
        for (int m = 0; m < 4; ++m) {
            int row0 = bm * 128 + wr * 64 + m * 16 + lg * 4;
            #pragma unroll
            for (int j = 0; j < 4; ++j) {
                float o = fmaxf(acc[m][n][j] + bv, 0.0f);
                Y[(size_t)(row0 + j) * LDY + col] = __float2bfloat16(o);
            }
        }
    }
}

// ---------------- alpha + rgb heads ----------------
__global__ __launch_bounds__(256) void finalize(const bf16* __restrict__ X2,
                                                const bf16* __restrict__ A4,
                                                const float* __restrict__ w_alpha,
                                                const float* __restrict__ b_alpha,
                                                const float* __restrict__ w_rgb,
                                                const float* __restrict__ b_rgb,
                                                float* __restrict__ out) {
    int t = threadIdx.x;
    int lane = t & 63, w = t >> 6;
    int n = blockIdx.x * 4 + w;
    float sa = 0.0f;
    #pragma unroll
    for (int i = 0; i < 4; ++i)
        sa = fmaf(__bfloat162float(X2[(size_t)n * 352 + lane + 64 * i]), w_alpha[lane + 64 * i], sa);
    float sr = 0.0f, sg = 0.0f, sb = 0.0f;
    #pragma unroll
    for (int i = 0; i < 2; ++i) {
        float a4 = __bfloat162float(A4[(size_t)n * 128 + lane + 64 * i]);
        sr = fmaf(a4, w_rgb[0 * 128 + lane + 64 * i], sr);
        sg = fmaf(a4, w_rgb[1 * 128 + lane + 64 * i], sg);
        sb = fmaf(a4, w_rgb[2 * 128 + lane + 64 * i], sb);
    }
    #pragma unroll
    for (int off = 32; off; off >>= 1) {
        sa += __shfl_xor(sa, off, 64);
        sr += __shfl_xor(sr, off, 64);
        sg += __shfl_xor(sg, off, 64);
        sb += __shfl_xor(sb, off, 64);
    }
    if (lane == 0) {
        out[(size_t)n * 4 + 0] = sa + b_alpha[0];
        out[(size_t)n * 4 + 1] = sr + b_rgb[0];
        out[(size_t)n * 4 + 2] = sg + b_rgb[1];
        out[(size_t)n * 4 + 3] = sb + b_rgb[2];
    }
}

extern "C" void kernel_launch(void* const* d_in, const int* in_sizes, int n_in,
                              void* d_out, int out_size, void* d_ws, size_t ws_size,
                              hipStream_t stream) {
    (void)in_sizes; (void)n_in; (void)out_size; (void)ws_size;
    const float* sampled_pts  = (const float*)d_in[0];
    const float* smpl_verts   = (const float*)d_in[1];
    const float* view_dir     = (const float*)d_in[2];
    const float* input_latent = (const float*)d_in[3];
    const float* vts_uv       = (const float*)d_in[4];
    const float* w_geo0 = (const float*)d_in[5];
    const float* b_geo0 = (const float*)d_in[6];
    const float* w_geo1 = (const float*)d_in[7];
    const float* b_geo1 = (const float*)d_in[8];
    const float* w_alpha = (const float*)d_in[9];
    const float* b_alpha = (const float*)d_in[10];
    const float* w_view0 = (const float*)d_in[11];
    const float* b_view0 = (const float*)d_in[12];
    const float* w_view1 = (const float*)d_in[13];
    const float* b_view1 = (const float*)d_in[14];
    const float* w_rgb = (const float*)d_in[15];
    const float* b_rgb = (const float*)d_in[16];

    char* ws = (char*)d_ws;
    size_t off = 0;
    auto alloc = [&](size_t bytes) { void* p = ws + off; off += (bytes + 255) & ~(size_t)255; return p; };
    bf16* latT = (bf16*)alloc((size_t)C_LAT * RESO * RESO * 2);     // 25.2 MB
    float* pd2 = (float*)alloc((size_t)N_PTS * NCHUNK * 4);         // 1 MB
    int*   pidx = (int*)alloc((size_t)N_PTS * NCHUNK * 4);          // 1 MB
    bf16* X1 = (bf16*)alloc((size_t)N_PTS * 128 * 2);               // 4.2 MB (A4 overlays)
    bf16* A1 = (bf16*)alloc((size_t)N_PTS * 256 * 2);               // 8.4 MB (A3 overlays)
    bf16* X2 = (bf16*)alloc((size_t)N_PTS * 352 * 2);               // 11.5 MB
    bf16* Wp0 = (bf16*)alloc((size_t)256 * 128 * 2);
    bf16* W1b = (bf16*)alloc((size_t)256 * 256 * 2);
    bf16* Wp2 = (bf16*)alloc((size_t)256 * 352 * 2);
    bf16* W3b = (bf16*)alloc((size_t)128 * 256 * 2);
    bf16* A3 = A1;   // net0 dead after L1
    bf16* A4 = X1;   // X1 dead after L0

    float* out = (float*)d_out;

    hipLaunchKernelGGL(transpose_latent, dim3(1024), dim3(256), 0, stream, input_latent, latT);
    hipLaunchKernelGGL(nn_partial, dim3(64, 16), dim3(256), 0, stream,
                       sampled_pts, smpl_verts, pd2, pidx);
    hipLaunchKernelGGL(prep_weights, dim3(352), dim3(256), 0, stream,
                       w_geo0, w_geo1, w_view0, w_view1, Wp0, W1b, Wp2, W3b);
    hipLaunchKernelGGL(sample_embed, dim3(4096), dim3(256), 0, stream,
                       pd2, pidx, vts_uv, latT, view_dir, X1, X2);
    // L0: X1[16384,128] * Wp0[256,128]^T -> A1 [16384,256]
    hipLaunchKernelGGL((gemm_mfma<128, 128, 128, 256>), dim3(N_PTS / 128, 2), dim3(256), 0, stream,
                       X1, Wp0, b_geo0, A1);
    // L1: A1 * W1b[256,256]^T -> X2 cols 0..255 (ldy=352)
    hipLaunchKernelGGL((gemm_mfma<256, 256, 256, 352>), dim3(N_PTS / 128, 2), dim3(256), 0, stream,
                       A1, W1b, b_geo1, X2);
    // L2: X2[16384,352] * Wp2[256,352]^T -> A3 [16384,256]
    hipLaunchKernelGGL((gemm_mfma<352, 352, 352, 256>), dim3(N_PTS / 128, 2), dim3(256), 0, stream,
                       X2, Wp2, b_view0, A3);
    // L3: A3 * W3b[128,256]^T -> A4 [16384,128]
    hipLaunchKernelGGL((gemm_mfma<256, 256, 256, 128>), dim3(N_PTS / 128, 1), dim3(256), 0, stream,
                       A3, W3b, b_view1, A4);
    hipLaunchKernelGGL(finalize, dim3(4096), dim3(256), 0, stream,
                       X2, A4, w_alpha, b_alpha, w_rgb, b_rgb, out);
}